// Round 10
// baseline (155.500 us; speedup 1.0000x reference)
//
#include <hip/hip_runtime.h>
#include <stdint.h>

typedef __attribute__((ext_vector_type(8))) __bf16 bf16x8;
typedef __attribute__((ext_vector_type(8))) unsigned short ushort8;
typedef __attribute__((ext_vector_type(4))) float f32x4;

static __device__ __forceinline__ unsigned short f2bf(float f) {
  unsigned u = __float_as_uint(f);
  u += 0x7fffu + ((u >> 16) & 1u);
  return (unsigned short)(u >> 16);
}

union U16cast { ushort8 u; bf16x8 b; };
static __device__ __forceinline__ bf16x8 as_bf16x8(ushort8 x) { U16cast t; t.u = x; return t.b; }
static __device__ __forceinline__ bf16x8 ldfrag(const unsigned short* p) {
  return as_bf16x8(*(const ushort8*)p);
}

#define MFMA16(a, b, c) __builtin_amdgcn_mfma_f32_16x16x32_bf16((a), (b), (c), 0, 0, 0)

#define GLD_LDS16(g, l)                                                        \
  __builtin_amdgcn_global_load_lds(                                            \
      (const __attribute__((address_space(1))) void*)(g),                      \
      (__attribute__((address_space(3))) void*)(l), 16, 0, 0)

// ---------------- merged cast f32 -> bf16 + zero l ---------------------------
__global__ __launch_bounds__(256) void cast_all(
    const float* __restrict__ x, const float* __restrict__ Wq,
    const float* __restrict__ Wk, const float* __restrict__ Wv,
    unsigned short* __restrict__ out, float* __restrict__ lzero,
    long nx4, long nw4, long n4) {
  long g = (long)blockIdx.x * blockDim.x + threadIdx.x;
  if (g < 2048) ((float4*)lzero)[g] = (float4){0.f, 0.f, 0.f, 0.f};  // l[8192]=0
  long i = g;
  long stride = (long)gridDim.x * blockDim.x;
  for (; i < n4; i += stride) {
    const float4* src;
    long j = i;
    if (j < nx4) {
      src = (const float4*)x;
    } else {
      j -= nx4;
      if (j < nw4) src = (const float4*)Wq;
      else if (j < 2 * nw4) { src = (const float4*)Wk; j -= nw4; }
      else { src = (const float4*)Wv; j -= 2 * nw4; }
    }
    float4 v = src[j];
    ushort4 o;
    o.x = f2bf(v.x); o.y = f2bf(v.y); o.z = f2bf(v.z); o.w = f2bf(v.w);
    *(ushort4*)(out + i * 4) = o;
  }
}

// ---- QKV GEMM r10: r9 geometry/pipeline, minimal sync ----------------------
// 256x384, BK=32, grid 256 = 1/CU, tri-buffer stage-kt+2 (depth 1.5 tiles).
// r9's 8 barriers/kt were scheduling enforcement only (reads hit buf c0,
// stages hit buf c2 != c0,c1 -> no intra-tile hazard). Correctness-minimal
// sync: ONE vmcnt + ONE barrier per tile boundary.
//   Ledger: prologue leaves 10 outstanding (t0,t1). Top of kt: vmcnt(5)
//   retires tile kt's 5 loads (vmcnt(0) at kt=31); barrier additionally
//   proves all waves finished READING buf c2's old tile (kt-1) before the
//   5 gloads for kt+2 are issued post-barrier. sched_barrier(0) pins the
//   gloads early; reads+MFMA (two mh-halves) are compiler-scheduled.
// Epilogue/swizzle/addressing = r8/r9-proven.
__global__ __launch_bounds__(512, 2) void gemm_qkv(
    const unsigned short* __restrict__ A, const unsigned short* __restrict__ B,
    unsigned short* __restrict__ qkv, unsigned short* __restrict__ vT) {
  __shared__ __align__(16) unsigned short As[3][8192];    // [buf][256*32] 48 KB
  __shared__ __align__(16) unsigned short Bs[3][12288];   // [buf][384*32] 72 KB

  int wg = blockIdx.x;
  wg = (wg & 7) * 32 + (wg >> 3);            // XCD swizzle, 256 = 8*32
  const int bm = wg >> 3, bn = wg & 7;
  const int m0 = bm << 8;                    // 0..31 * 256
  const int n0 = bn * 384;                   // 0..7  * 384

  const int tid = threadIdx.x;

  const int srow = tid >> 2;                 // 0..127
  const int sseg = (tid & 3) ^ ((srow >> 1) & 3);
  const unsigned short* sa = A + (long)(m0 + srow) * 1024 + sseg * 8;
  const unsigned short* sb = B + (long)(n0 + srow) * 1024 + sseg * 8;
  unsigned short* dA = &As[0][0] + tid * 8;
  unsigned short* dB = &Bs[0][0] + tid * 8;

  // A: 2 rounds of 128 rows; B: 3 rounds of 128 rows. 5 gloads/thread/tile.
#define SA0(kt, bu) GLD_LDS16(sa + (kt) * 32,          dA + (bu) * 8192)
#define SA1(kt, bu) GLD_LDS16(sa + 131072 + (kt) * 32, dA + (bu) * 8192 + 4096)
#define SB0(kt, bu) GLD_LDS16(sb + (kt) * 32,          dB + (bu) * 12288)
#define SB1(kt, bu) GLD_LDS16(sb + 131072 + (kt) * 32, dB + (bu) * 12288 + 4096)
#define SB2(kt, bu) GLD_LDS16(sb + 262144 + (kt) * 32, dB + (bu) * 12288 + 8192)

  const int lane = tid & 63;
  const int w = tid >> 6;
  const int wrm = w >> 2;    // 0..1 (M half: 128 rows)
  const int wcn = w & 3;     // 0..3 (N quarter: 96 cols)
  const int fr = lane & 15;
  const int kb = lane >> 4;
  const int segr = (kb ^ ((fr >> 1) & 3)) << 3;
  const unsigned short* rA = &As[0][0] + (wrm * 128 + fr) * 32 + segr;
  const unsigned short* rB = &Bs[0][0] + (wcn * 96 + fr) * 32 + segr;

  f32x4 acc[8][6];
#pragma unroll
  for (int mf = 0; mf < 8; ++mf)
#pragma unroll
    for (int nf = 0; nf < 6; ++nf)
      acc[mf][nf] = (f32x4){0.f, 0.f, 0.f, 0.f};

  // prologue: tile0 -> buf0, tile1 -> buf1 (10 loads in flight)
  SA0(0, 0); SA1(0, 0); SB0(0, 0); SB1(0, 0); SB2(0, 0);
  SA0(1, 1); SA1(1, 1); SB0(1, 1); SB1(1, 1); SB2(1, 1);

  int c0 = 0, c2 = 2;                        // read buf, stage buf (kt+2)
#pragma unroll 1
  for (int kt = 0; kt < 32; ++kt) {
    // ---- tile-boundary sync: buf c0 ready, buf c2 free -------------------
    if (kt < 31) asm volatile("s_waitcnt vmcnt(5)" ::: "memory");
    else         asm volatile("s_waitcnt vmcnt(0)" ::: "memory");
    __builtin_amdgcn_s_barrier();
    __builtin_amdgcn_sched_barrier(0);

    // ---- issue next-next tile's staging first (pinned early) -------------
    if (kt < 30) {
      const int k2 = kt + 2;
      SA0(k2, c2); SA1(k2, c2); SB0(k2, c2); SB1(k2, c2); SB2(k2, c2);
    }
    __builtin_amdgcn_sched_barrier(0);

    const unsigned short* pA = rA + c0 * 8192;
    const unsigned short* pB = rB + c0 * 12288;
    bf16x8 a[4], bv[6];

    // ---- mh0 half: reads + 24 MFMA (compiler-scheduled) ------------------
#pragma unroll
    for (int nf = 0; nf < 6; ++nf) bv[nf] = ldfrag(pB + nf * 512);
#pragma unroll
    for (int mf = 0; mf < 4; ++mf) a[mf] = ldfrag(pA + mf * 512);
    __builtin_amdgcn_s_setprio(1);
#pragma unroll
    for (int mf = 0; mf < 4; ++mf)
#pragma unroll
      for (int nf = 0; nf < 6; ++nf)
        acc[mf][nf] = MFMA16(a[mf], bv[nf], acc[mf][nf]);
    __builtin_amdgcn_s_setprio(0);

    // ---- mh1 half --------------------------------------------------------
#pragma unroll
    for (int mf = 0; mf < 4; ++mf) a[mf] = ldfrag(pA + 2048 + mf * 512);
    __builtin_amdgcn_s_setprio(1);
#pragma unroll
    for (int mf = 0; mf < 4; ++mf)
#pragma unroll
      for (int nf = 0; nf < 6; ++nf)
        acc[4 + mf][nf] = MFMA16(a[mf], bv[nf], acc[4 + mf][nf]);
    __builtin_amdgcn_s_setprio(0);

    c0 = (c0 == 2) ? 0 : c0 + 1;
    c2 = (c2 == 2) ? 0 : c2 + 1;
  }
#undef SA0
#undef SA1
#undef SB0
#undef SB1
#undef SB2

  // ---- epilogue (r8-proven): route to qkv (cols<2048) or vT (v region) ----
  const int rq = kb << 2;
#pragma unroll
  for (int mf = 0; mf < 8; ++mf) {
    const int row = m0 + wrm * 128 + mf * 16 + rq;
#pragma unroll
    for (int nf = 0; nf < 6; ++nf) {
      const int colb = n0 + wcn * 96 + nf * 16;   // fragment col base (wave-uniform)
      if (colb < 2048) {
        const int col = colb + fr;
#pragma unroll
        for (int r = 0; r < 4; ++r)
          qkv[(long)(row + r) * 3072 + col] = f2bf(acc[mf][nf][r]);
      } else {
        const int b2 = m0 >> 11;
        const int trow = (m0 & 2047) + wrm * 128 + mf * 16 + rq;
        const int colv = colb - 2048 + fr;
        ushort4 o;
        o.x = f2bf(acc[mf][nf][0]); o.y = f2bf(acc[mf][nf][1]);
        o.z = f2bf(acc[mf][nf][2]); o.w = f2bf(acc[mf][nf][3]);
        *(ushort4*)(vT + ((long)b2 * 1024 + colv) * 2048 + trow) = o;
      }
    }
  }
}

// ---------------- 128x128 GEMM engine for S and PV (r0-proven) --------------
//  MODE 1 S:   triangular grid (544, z fastest): A=q, B=k (stride 3072).
//              Epilogue: Pu = exp(s/32) (causal-masked -> exact 0) stored bf16,
//              plus per-row partial sums reduced over the 16 fr-lanes and
//              atomicAdd'ed into l[b*2048+row].
//  MODE 2 PV:  512 blocks; XCD-banded bn-sweep + per-XCD LPT; causal
//              kend=m0+128; A=Pu, B=vT. Epilogue: out = acc * (1/l[row]);
//              1/l loads+rcp hoisted above the K-loop (r6-proven).
template <int MODE>
__global__ __launch_bounds__(256, 4) void gemm128(
    const unsigned short* __restrict__ A, const unsigned short* __restrict__ Bp,
    void* __restrict__ Cout, float* __restrict__ lbuf) {
  __shared__ __align__(16) unsigned short As[2][4096];
  __shared__ __align__(16) unsigned short Bs[2][4096];

  constexpr int LDA = (MODE == 1) ? 3072 : 2048;

  const int wgid = blockIdx.x;
  int m0, n0, b;
  if constexpr (MODE == 1) {
    b = wgid & 3;
    const int t = wgid >> 2;                    // 0..135
    int bm = 0;
    while ((bm + 2) * (bm + 1) / 2 <= t) ++bm;
    const int bn = t - bm * (bm + 1) / 2;
    m0 = bm << 7; n0 = bn << 7;
  } else {
    const int xcd = wgid & 7;
    const int inner = wgid >> 3;                // 0..63
    const int s = inner >> 5;
    const int rem = inner & 31;
    b = rem >> 3;
    const int bn = rem & 7;
    const int bm = s ? (15 - xcd) : xcd;
    m0 = bm << 7; n0 = bn << 7;
  }

  const unsigned short* Ab = A;
  const unsigned short* Bb = Bp;
  if constexpr (MODE == 1) {
    Ab += (long)b * 2048 * 3072;
    Bb += (long)b * 2048 * 3072;
  } else {
    Ab += (long)b * 2048 * 2048;
    Bb += (long)b * 1024 * 2048;
  }

  const int tid = threadIdx.x;

  const int srow = tid >> 2;                       // 0..63
  const int sseg = (tid & 3) ^ ((srow >> 1) & 3);
  const unsigned short* sa = Ab + (long)(m0 + srow) * LDA + sseg * 8;
  const unsigned short* sb = Bb + (long)(n0 + srow) * LDA + sseg * 8;
  const long sRj = (long)64 * LDA;
  unsigned short* dA = &As[0][0] + tid * 8;
  unsigned short* dB = &Bs[0][0] + tid * 8;

#define STG(kt, s)                                                             \
  do {                                                                         \
    GLD_LDS16(sa + (kt) * 32, dA + (s) * 4096);                                \
    GLD_LDS16(sa + sRj + (kt) * 32, dA + (s) * 4096 + 2048);                   \
    GLD_LDS16(sb + (kt) * 32, dB + (s) * 4096);                                \
    GLD_LDS16(sb + sRj + (kt) * 32, dB + (s) * 4096 + 2048);                   \
  } while (0)

  const int lane = tid & 63;
  const int w = tid >> 6;
  const int wr = w >> 1;
  const int wc = w & 1;
  const int fr = lane & 15;
  const int kb = lane >> 4;
  const unsigned short* rA0 = &As[0][0] + wr * 64 * 32;
  const unsigned short* rB0 = &Bs[0][0] + wc * 64 * 32;

  const int rq = kb << 2;

  // PV-only: hoist loop-invariant 1/l above the K-loop
  float il[4][4];
  if constexpr (MODE == 2) {
    const float* lrow = lbuf + b * 2048;
#pragma unroll
    for (int mf = 0; mf < 4; ++mf) {
      const int row = m0 + wr * 64 + mf * 16 + rq;
#pragma unroll
      for (int r = 0; r < 4; ++r) il[mf][r] = 1.0f / lrow[row + r];
    }
  }

  f32x4 acc[4][4];
#pragma unroll
  for (int mf = 0; mf < 4; ++mf)
#pragma unroll
    for (int nf = 0; nf < 4; ++nf)
      acc[mf][nf] = (f32x4){0.f, 0.f, 0.f, 0.f};

  const int kend = (MODE == 2) ? (m0 + 128) : 1024;
  const int NT = kend >> 5;

  STG(0, 0);
  __syncthreads();

  for (int kt = 0; kt < NT; ++kt) {
    const int s = kt & 1;
    if (kt + 1 < NT) STG(kt + 1, s ^ 1);

    bf16x8 av[4], bvv[4];
#pragma unroll
    for (int mf = 0; mf < 4; ++mf) {
      const int row = mf * 16 + fr;
      const int segr = (kb ^ ((row >> 1) & 3)) << 3;
      av[mf] = ldfrag(rA0 + s * 4096 + row * 32 + segr);
    }
#pragma unroll
    for (int nf = 0; nf < 4; ++nf) {
      const int row = nf * 16 + fr;
      const int segr = (kb ^ ((row >> 1) & 3)) << 3;
      bvv[nf] = ldfrag(rB0 + s * 4096 + row * 32 + segr);
    }

#pragma unroll
    for (int mf = 0; mf < 4; ++mf)
#pragma unroll
      for (int nf = 0; nf < 4; ++nf)
        acc[mf][nf] = MFMA16(av[mf], bvv[nf], acc[mf][nf]);

    __syncthreads();
  }
#undef STG

  if constexpr (MODE == 1) {
    unsigned short* Pu = (unsigned short*)Cout + (long)b * 2048 * 2048;
    float* lrow = lbuf + b * 2048;
#pragma unroll
    for (int mf = 0; mf < 4; ++mf) {
      const int row = m0 + wr * 64 + mf * 16 + rq;
      float psum0 = 0.f, psum1 = 0.f, psum2 = 0.f, psum3 = 0.f;
#pragma unroll
      for (int nf = 0; nf < 4; ++nf) {
        const int col = n0 + wc * 64 + nf * 16 + fr;
        float e0 = (col > row + 0) ? 0.f : __expf(acc[mf][nf][0] * 0.03125f);
        float e1 = (col > row + 1) ? 0.f : __expf(acc[mf][nf][1] * 0.03125f);
        float e2 = (col > row + 2) ? 0.f : __expf(acc[mf][nf][2] * 0.03125f);
        float e3 = (col > row + 3) ? 0.f : __expf(acc[mf][nf][3] * 0.03125f);
        psum0 += e0; psum1 += e1; psum2 += e2; psum3 += e3;
        Pu[(long)(row + 0) * 2048 + col] = f2bf(e0);
        Pu[(long)(row + 1) * 2048 + col] = f2bf(e1);
        Pu[(long)(row + 2) * 2048 + col] = f2bf(e2);
        Pu[(long)(row + 3) * 2048 + col] = f2bf(e3);
      }
      // reduce over the 16 fr-lanes (xor 1,2,4,8 stays in the 16-group)
#pragma unroll
      for (int off = 1; off < 16; off <<= 1) {
        psum0 += __shfl_xor(psum0, off);
        psum1 += __shfl_xor(psum1, off);
        psum2 += __shfl_xor(psum2, off);
        psum3 += __shfl_xor(psum3, off);
      }
      if (fr == 0) {
        atomicAdd(&lrow[row + 0], psum0);
        atomicAdd(&lrow[row + 1], psum1);
        atomicAdd(&lrow[row + 2], psum2);
        atomicAdd(&lrow[row + 3], psum3);
      }
    }
  } else {
    float* Cf = (float*)Cout + (long)b * 2048 * 1024;
#pragma unroll
    for (int mf = 0; mf < 4; ++mf) {
      const int row = m0 + wr * 64 + mf * 16 + rq;
#pragma unroll
      for (int nf = 0; nf < 4; ++nf) {
        const int col = n0 + wc * 64 + nf * 16 + fr;
        Cf[(long)(row + 0) * 1024 + col] = acc[mf][nf][0] * il[mf][0];
        Cf[(long)(row + 1) * 1024 + col] = acc[mf][nf][1] * il[mf][1];
        Cf[(long)(row + 2) * 1024 + col] = acc[mf][nf][2] * il[mf][2];
        Cf[(long)(row + 3) * 1024 + col] = acc[mf][nf][3] * il[mf][3];
      }
    }
  }
}

// ---------------------------------------------------------------------------
extern "C" void kernel_launch(void* const* d_in, const int* in_sizes, int n_in,
                              void* d_out, int out_size, void* d_ws, size_t ws_size,
                              hipStream_t stream) {
  const float* x  = (const float*)d_in[0];
  const float* Wq = (const float*)d_in[1];
  const float* Wk = (const float*)d_in[2];
  const float* Wv = (const float*)d_in[3];
  float* out = (float*)d_out;

  const int Bb = 4, T = 2048, C = 1024;
  const long BT = (long)Bb * T;  // 8192
  const int N3 = 3 * C;          // 3072

  char* ws = (char*)d_ws;
  unsigned short* xb   = (unsigned short*)ws; ws += BT * C * 2;            // 16 MB
  unsigned short* wbuf = (unsigned short*)ws; ws += (long)N3 * C * 2;      // 6 MB
  unsigned short* qkv  = (unsigned short*)ws; ws += BT * N3 * 2;           // 48 MB (v cols unused)
  unsigned short* vT   = (unsigned short*)ws; ws += BT * C * 2;            // 16 MB
  unsigned short* Pu   = (unsigned short*)ws; ws += (long)Bb * T * T * 2;  // 32 MB
  float* lbuf          = (float*)ws;          ws += BT * 4;                // 32 KB

  // 1. merged casts + zero l
  const long nx4 = BT * C / 4, nw4 = (long)C * C / 4;
  cast_all<<<2048, 256, 0, stream>>>(x, Wq, Wk, Wv, xb, lbuf, nx4, nw4, nx4 + 3 * nw4);

  // 2. fused QKV projection (256x384, 1/CU, minimal-sync tri-buffer); v -> vT
  gemm_qkv<<<dim3(256, 1, 1), 512, 0, stream>>>(xb, wbuf, qkv, vT);

  // 3. Pu = exp(q k^T / 32) (causal, no-max softmax) + atomic row sums -> l
  gemm128<1><<<dim3(544, 1, 1), 256, 0, stream>>>(qkv, qkv + C, Pu, lbuf);

  // 4. out = (Pu vT) / l (causal K, XCD-banded bn-sweep + per-XCD LPT)
  gemm128<2><<<dim3(512, 1, 1), 256, 0, stream>>>(Pu, vT, out, lbuf);
}

// Round 11
// 149.349 us; speedup vs baseline: 1.0412x; 1.0412x over previous
//
#include <hip/hip_runtime.h>
#include <stdint.h>

typedef __attribute__((ext_vector_type(8))) __bf16 bf16x8;
typedef __attribute__((ext_vector_type(8))) unsigned short ushort8;
typedef __attribute__((ext_vector_type(4))) float f32x4;

static __device__ __forceinline__ unsigned short f2bf(float f) {
  unsigned u = __float_as_uint(f);
  u += 0x7fffu + ((u >> 16) & 1u);
  return (unsigned short)(u >> 16);
}

union U16cast { ushort8 u; bf16x8 b; };
static __device__ __forceinline__ bf16x8 as_bf16x8(ushort8 x) { U16cast t; t.u = x; return t.b; }
static __device__ __forceinline__ bf16x8 ldfrag(const unsigned short* p) {
  return as_bf16x8(*(const ushort8*)p);
}

#define MFMA16(a, b, c) __builtin_amdgcn_mfma_f32_16x16x32_bf16((a), (b), (c), 0, 0, 0)

#define GLD_LDS16(g, l)                                                        \
  __builtin_amdgcn_global_load_lds(                                            \
      (const __attribute__((address_space(1))) void*)(g),                      \
      (__attribute__((address_space(3))) void*)(l), 16, 0, 0)

// ---------------- merged cast f32 -> bf16 + zero l ---------------------------
__global__ __launch_bounds__(256) void cast_all(
    const float* __restrict__ x, const float* __restrict__ Wq,
    const float* __restrict__ Wk, const float* __restrict__ Wv,
    unsigned short* __restrict__ out, float* __restrict__ lzero,
    long nx4, long nw4, long n4) {
  long g = (long)blockIdx.x * blockDim.x + threadIdx.x;
  if (g < 2048) ((float4*)lzero)[g] = (float4){0.f, 0.f, 0.f, 0.f};  // l[8192]=0
  long i = g;
  long stride = (long)gridDim.x * blockDim.x;
  for (; i < n4; i += stride) {
    const float4* src;
    long j = i;
    if (j < nx4) {
      src = (const float4*)x;
    } else {
      j -= nx4;
      if (j < nw4) src = (const float4*)Wq;
      else if (j < 2 * nw4) { src = (const float4*)Wk; j -= nw4; }
      else { src = (const float4*)Wv; j -= 2 * nw4; }
    }
    float4 v = src[j];
    ushort4 o;
    o.x = f2bf(v.x); o.y = f2bf(v.y); o.z = f2bf(v.z); o.w = f2bf(v.w);
    *(ushort4*)(out + i * 4) = o;
  }
}

// ---- QKV GEMM r11 (= r9-proven): 256x384, BK=32, grid 256 = 1/CU, m201 ----
// 4-phase tri-buffer schedule. Stage tile kt+2 during kt (pipeline depth 1.5
// tiles): all ds_reads issue PRE-barrier against data whose vmcnt cleared a
// full K-tile earlier. One counted wait per kt: vmcnt(5) at ph3 (retires
// tile kt+1's 5 loads; kt+2's stay in flight; 0 only at kt=30).
// Phase = {reads+stages; bar; lgkm0; sched_bar; prio1; 12 MFMA; prio0; bar}.
//   ph0: read a0[4](mh0), b0[3](nh0); stage A0,A1(kt+2); MFMA mh0 x nh0
//   ph1: read b1[3](nh1);             stage B0,B1(kt+2); MFMA mh0 x nh1
//   ph2: read a1[4](mh1);             stage B2(kt+2);    MFMA mh1 x nh0
//   ph3: (b1 live)                    vmcnt(5);          MFMA mh1 x nh1
// LDS 3x40 KB = 120 KB (1 block/CU).
// r9/r10 A/B CONCLUSION: the per-phase barrier lockstep IS the win mechanism
// (r9 64us vs r10 minimal-sync 71us) — it forces wave-groups into
// complementary {ds_read | MFMA} slots so the LDS pipe and MFMA pipe overlap
// across waves. Do not remove the phase barriers.
__global__ __launch_bounds__(512, 2) void gemm_qkv(
    const unsigned short* __restrict__ A, const unsigned short* __restrict__ B,
    unsigned short* __restrict__ qkv, unsigned short* __restrict__ vT) {
  __shared__ __align__(16) unsigned short As[3][8192];    // [buf][256*32] 48 KB
  __shared__ __align__(16) unsigned short Bs[3][12288];   // [buf][384*32] 72 KB

  int wg = blockIdx.x;
  wg = (wg & 7) * 32 + (wg >> 3);            // XCD swizzle, 256 = 8*32
  const int bm = wg >> 3, bn = wg & 7;
  const int m0 = bm << 8;                    // 0..31 * 256
  const int n0 = bn * 384;                   // 0..7  * 384

  const int tid = threadIdx.x;

  const int srow = tid >> 2;                 // 0..127
  const int sseg = (tid & 3) ^ ((srow >> 1) & 3);
  const unsigned short* sa = A + (long)(m0 + srow) * 1024 + sseg * 8;
  const unsigned short* sb = B + (long)(n0 + srow) * 1024 + sseg * 8;
  unsigned short* dA = &As[0][0] + tid * 8;
  unsigned short* dB = &Bs[0][0] + tid * 8;

  // A: 2 rounds of 128 rows; B: 3 rounds of 128 rows. 5 gloads/thread/tile.
#define SA0(kt, bu) GLD_LDS16(sa + (kt) * 32,          dA + (bu) * 8192)
#define SA1(kt, bu) GLD_LDS16(sa + 131072 + (kt) * 32, dA + (bu) * 8192 + 4096)
#define SB0(kt, bu) GLD_LDS16(sb + (kt) * 32,          dB + (bu) * 12288)
#define SB1(kt, bu) GLD_LDS16(sb + 131072 + (kt) * 32, dB + (bu) * 12288 + 4096)
#define SB2(kt, bu) GLD_LDS16(sb + 262144 + (kt) * 32, dB + (bu) * 12288 + 8192)

  const int lane = tid & 63;
  const int w = tid >> 6;
  const int wrm = w >> 2;    // 0..1 (M half: 128 rows)
  const int wcn = w & 3;     // 0..3 (N quarter: 96 cols)
  const int fr = lane & 15;
  const int kb = lane >> 4;
  const int segr = (kb ^ ((fr >> 1) & 3)) << 3;
  const unsigned short* rA = &As[0][0] + (wrm * 128 + fr) * 32 + segr;
  const unsigned short* rB = &Bs[0][0] + (wcn * 96 + fr) * 32 + segr;

  f32x4 acc[8][6];
#pragma unroll
  for (int mf = 0; mf < 8; ++mf)
#pragma unroll
    for (int nf = 0; nf < 6; ++nf)
      acc[mf][nf] = (f32x4){0.f, 0.f, 0.f, 0.f};

  // prologue: tile0 -> buf0, tile1 -> buf1 (steady slot order);
  // wait tile0 complete, keep tile1's 5 loads in flight.
  SA0(0, 0); SA1(0, 0); SB0(0, 0); SB1(0, 0); SB2(0, 0);
  SA0(1, 1); SA1(1, 1); SB0(1, 1); SB1(1, 1); SB2(1, 1);
  asm volatile("s_waitcnt vmcnt(5)" ::: "memory");
  __builtin_amdgcn_s_barrier();
  __builtin_amdgcn_sched_barrier(0);

  int c0 = 0, c2 = 2;                        // read buf, stage buf (kt+2)
#pragma unroll 1
  for (int kt = 0; kt < 32; ++kt) {
    const unsigned short* pA = rA + c0 * 8192;
    const unsigned short* pB = rB + c0 * 12288;
    const int k2 = kt + 2;
    const bool st = (kt < 30);
    bf16x8 a[4], b0v[3], b1v[3];

    // -------- ph0: MFMA (mh0 x nh0); reads a0,b0; stage A(kt+2) ----------
#pragma unroll
    for (int mf = 0; mf < 4; ++mf) a[mf] = ldfrag(pA + mf * 512);
#pragma unroll
    for (int nf = 0; nf < 3; ++nf) b0v[nf] = ldfrag(pB + nf * 512);
    if (st) { SA0(k2, c2); SA1(k2, c2); }
    __builtin_amdgcn_s_barrier();
    asm volatile("s_waitcnt lgkmcnt(0)" ::: "memory");
    __builtin_amdgcn_sched_barrier(0);
    __builtin_amdgcn_s_setprio(1);
#pragma unroll
    for (int mf = 0; mf < 4; ++mf)
#pragma unroll
      for (int nf = 0; nf < 3; ++nf)
        acc[mf][nf] = MFMA16(a[mf], b0v[nf], acc[mf][nf]);
    __builtin_amdgcn_s_setprio(0);
    __builtin_amdgcn_s_barrier();

    // -------- ph1: MFMA (mh0 x nh1); reads b1; stage B01(kt+2) -----------
#pragma unroll
    for (int nf = 0; nf < 3; ++nf) b1v[nf] = ldfrag(pB + (3 + nf) * 512);
    if (st) { SB0(k2, c2); SB1(k2, c2); }
    __builtin_amdgcn_s_barrier();
    asm volatile("s_waitcnt lgkmcnt(0)" ::: "memory");
    __builtin_amdgcn_sched_barrier(0);
    __builtin_amdgcn_s_setprio(1);
#pragma unroll
    for (int mf = 0; mf < 4; ++mf)
#pragma unroll
      for (int nf = 0; nf < 3; ++nf)
        acc[mf][3 + nf] = MFMA16(a[mf], b1v[nf], acc[mf][3 + nf]);
    __builtin_amdgcn_s_setprio(0);
    __builtin_amdgcn_s_barrier();

    // -------- ph2: MFMA (mh1 x nh0); reads a1; stage B2(kt+2) ------------
#pragma unroll
    for (int mf = 0; mf < 4; ++mf) a[mf] = ldfrag(pA + 2048 + mf * 512);
    if (st) SB2(k2, c2);
    __builtin_amdgcn_s_barrier();
    asm volatile("s_waitcnt lgkmcnt(0)" ::: "memory");
    __builtin_amdgcn_sched_barrier(0);
    __builtin_amdgcn_s_setprio(1);
#pragma unroll
    for (int mf = 0; mf < 4; ++mf)
#pragma unroll
      for (int nf = 0; nf < 3; ++nf)
        acc[4 + mf][nf] = MFMA16(a[mf], b0v[nf], acc[4 + mf][nf]);
    __builtin_amdgcn_s_setprio(0);
    __builtin_amdgcn_s_barrier();

    // -------- ph3: MFMA (mh1 x nh1); vmcnt boundary for buf kt+1 ---------
    if (kt <= 29)      asm volatile("s_waitcnt vmcnt(5)" ::: "memory");
    else if (kt == 30) asm volatile("s_waitcnt vmcnt(0)" ::: "memory");
    __builtin_amdgcn_s_barrier();
    __builtin_amdgcn_sched_barrier(0);
    __builtin_amdgcn_s_setprio(1);
#pragma unroll
    for (int mf = 0; mf < 4; ++mf)
#pragma unroll
      for (int nf = 0; nf < 3; ++nf)
        acc[4 + mf][3 + nf] = MFMA16(a[mf], b1v[nf], acc[4 + mf][3 + nf]);
    __builtin_amdgcn_s_setprio(0);
    __builtin_amdgcn_s_barrier();

    c0 = (c0 == 2) ? 0 : c0 + 1;
    c2 = (c2 == 2) ? 0 : c2 + 1;
  }
#undef SA0
#undef SA1
#undef SB0
#undef SB1
#undef SB2

  // ---- epilogue (r8-proven): route to qkv (cols<2048) or vT (v region) ----
  const int rq = kb << 2;
#pragma unroll
  for (int mf = 0; mf < 8; ++mf) {
    const int row = m0 + wrm * 128 + mf * 16 + rq;
#pragma unroll
    for (int nf = 0; nf < 6; ++nf) {
      const int colb = n0 + wcn * 96 + nf * 16;   // fragment col base (wave-uniform)
      if (colb < 2048) {
        const int col = colb + fr;
#pragma unroll
        for (int r = 0; r < 4; ++r)
          qkv[(long)(row + r) * 3072 + col] = f2bf(acc[mf][nf][r]);
      } else {
        const int b2 = m0 >> 11;
        const int trow = (m0 & 2047) + wrm * 128 + mf * 16 + rq;
        const int colv = colb - 2048 + fr;
        ushort4 o;
        o.x = f2bf(acc[mf][nf][0]); o.y = f2bf(acc[mf][nf][1]);
        o.z = f2bf(acc[mf][nf][2]); o.w = f2bf(acc[mf][nf][3]);
        *(ushort4*)(vT + ((long)b2 * 1024 + colv) * 2048 + trow) = o;
      }
    }
  }
}

// ---------------- 128x128 GEMM engine for S and PV (r0-proven) --------------
//  MODE 1 S:   triangular grid (544, z fastest): A=q, B=k (stride 3072).
//              Epilogue: Pu = exp(s/32) (causal-masked -> exact 0) stored bf16,
//              plus per-row partial sums reduced over the 16 fr-lanes and
//              atomicAdd'ed into l[b*2048+row].
//  MODE 2 PV:  512 blocks; XCD-banded bn-sweep + per-XCD LPT; causal
//              kend=m0+128; A=Pu, B=vT. Epilogue: out = acc * (1/l[row]);
//              1/l loads+rcp hoisted above the K-loop (r6-proven).
template <int MODE>
__global__ __launch_bounds__(256, 4) void gemm128(
    const unsigned short* __restrict__ A, const unsigned short* __restrict__ Bp,
    void* __restrict__ Cout, float* __restrict__ lbuf) {
  __shared__ __align__(16) unsigned short As[2][4096];
  __shared__ __align__(16) unsigned short Bs[2][4096];

  constexpr int LDA = (MODE == 1) ? 3072 : 2048;

  const int wgid = blockIdx.x;
  int m0, n0, b;
  if constexpr (MODE == 1) {
    b = wgid & 3;
    const int t = wgid >> 2;                    // 0..135
    int bm = 0;
    while ((bm + 2) * (bm + 1) / 2 <= t) ++bm;
    const int bn = t - bm * (bm + 1) / 2;
    m0 = bm << 7; n0 = bn << 7;
  } else {
    const int xcd = wgid & 7;
    const int inner = wgid >> 3;                // 0..63
    const int s = inner >> 5;
    const int rem = inner & 31;
    b = rem >> 3;
    const int bn = rem & 7;
    const int bm = s ? (15 - xcd) : xcd;
    m0 = bm << 7; n0 = bn << 7;
  }

  const unsigned short* Ab = A;
  const unsigned short* Bb = Bp;
  if constexpr (MODE == 1) {
    Ab += (long)b * 2048 * 3072;
    Bb += (long)b * 2048 * 3072;
  } else {
    Ab += (long)b * 2048 * 2048;
    Bb += (long)b * 1024 * 2048;
  }

  const int tid = threadIdx.x;

  const int srow = tid >> 2;                       // 0..63
  const int sseg = (tid & 3) ^ ((srow >> 1) & 3);
  const unsigned short* sa = Ab + (long)(m0 + srow) * LDA + sseg * 8;
  const unsigned short* sb = Bb + (long)(n0 + srow) * LDA + sseg * 8;
  const long sRj = (long)64 * LDA;
  unsigned short* dA = &As[0][0] + tid * 8;
  unsigned short* dB = &Bs[0][0] + tid * 8;

#define STG(kt, s)                                                             \
  do {                                                                         \
    GLD_LDS16(sa + (kt) * 32, dA + (s) * 4096);                                \
    GLD_LDS16(sa + sRj + (kt) * 32, dA + (s) * 4096 + 2048);                   \
    GLD_LDS16(sb + (kt) * 32, dB + (s) * 4096);                                \
    GLD_LDS16(sb + sRj + (kt) * 32, dB + (s) * 4096 + 2048);                   \
  } while (0)

  const int lane = tid & 63;
  const int w = tid >> 6;
  const int wr = w >> 1;
  const int wc = w & 1;
  const int fr = lane & 15;
  const int kb = lane >> 4;
  const unsigned short* rA0 = &As[0][0] + wr * 64 * 32;
  const unsigned short* rB0 = &Bs[0][0] + wc * 64 * 32;

  const int rq = kb << 2;

  // PV-only: hoist loop-invariant 1/l above the K-loop
  float il[4][4];
  if constexpr (MODE == 2) {
    const float* lrow = lbuf + b * 2048;
#pragma unroll
    for (int mf = 0; mf < 4; ++mf) {
      const int row = m0 + wr * 64 + mf * 16 + rq;
#pragma unroll
      for (int r = 0; r < 4; ++r) il[mf][r] = 1.0f / lrow[row + r];
    }
  }

  f32x4 acc[4][4];
#pragma unroll
  for (int mf = 0; mf < 4; ++mf)
#pragma unroll
    for (int nf = 0; nf < 4; ++nf)
      acc[mf][nf] = (f32x4){0.f, 0.f, 0.f, 0.f};

  const int kend = (MODE == 2) ? (m0 + 128) : 1024;
  const int NT = kend >> 5;

  STG(0, 0);
  __syncthreads();

  for (int kt = 0; kt < NT; ++kt) {
    const int s = kt & 1;
    if (kt + 1 < NT) STG(kt + 1, s ^ 1);

    bf16x8 av[4], bvv[4];
#pragma unroll
    for (int mf = 0; mf < 4; ++mf) {
      const int row = mf * 16 + fr;
      const int segr = (kb ^ ((row >> 1) & 3)) << 3;
      av[mf] = ldfrag(rA0 + s * 4096 + row * 32 + segr);
    }
#pragma unroll
    for (int nf = 0; nf < 4; ++nf) {
      const int row = nf * 16 + fr;
      const int segr = (kb ^ ((row >> 1) & 3)) << 3;
      bvv[nf] = ldfrag(rB0 + s * 4096 + row * 32 + segr);
    }

#pragma unroll
    for (int mf = 0; mf < 4; ++mf)
#pragma unroll
      for (int nf = 0; nf < 4; ++nf)
        acc[mf][nf] = MFMA16(av[mf], bvv[nf], acc[mf][nf]);

    __syncthreads();
  }
#undef STG

  if constexpr (MODE == 1) {
    unsigned short* Pu = (unsigned short*)Cout + (long)b * 2048 * 2048;
    float* lrow = lbuf + b * 2048;
#pragma unroll
    for (int mf = 0; mf < 4; ++mf) {
      const int row = m0 + wr * 64 + mf * 16 + rq;
      float psum0 = 0.f, psum1 = 0.f, psum2 = 0.f, psum3 = 0.f;
#pragma unroll
      for (int nf = 0; nf < 4; ++nf) {
        const int col = n0 + wc * 64 + nf * 16 + fr;
        float e0 = (col > row + 0) ? 0.f : __expf(acc[mf][nf][0] * 0.03125f);
        float e1 = (col > row + 1) ? 0.f : __expf(acc[mf][nf][1] * 0.03125f);
        float e2 = (col > row + 2) ? 0.f : __expf(acc[mf][nf][2] * 0.03125f);
        float e3 = (col > row + 3) ? 0.f : __expf(acc[mf][nf][3] * 0.03125f);
        psum0 += e0; psum1 += e1; psum2 += e2; psum3 += e3;
        Pu[(long)(row + 0) * 2048 + col] = f2bf(e0);
        Pu[(long)(row + 1) * 2048 + col] = f2bf(e1);
        Pu[(long)(row + 2) * 2048 + col] = f2bf(e2);
        Pu[(long)(row + 3) * 2048 + col] = f2bf(e3);
      }
      // reduce over the 16 fr-lanes (xor 1,2,4,8 stays in the 16-group)
#pragma unroll
      for (int off = 1; off < 16; off <<= 1) {
        psum0 += __shfl_xor(psum0, off);
        psum1 += __shfl_xor(psum1, off);
        psum2 += __shfl_xor(psum2, off);
        psum3 += __shfl_xor(psum3, off);
      }
      if (fr == 0) {
        atomicAdd(&lrow[row + 0], psum0);
        atomicAdd(&lrow[row + 1], psum1);
        atomicAdd(&lrow[row + 2], psum2);
        atomicAdd(&lrow[row + 3], psum3);
      }
    }
  } else {
    float* Cf = (float*)Cout + (long)b * 2048 * 1024;
#pragma unroll
    for (int mf = 0; mf < 4; ++mf) {
      const int row = m0 + wr * 64 + mf * 16 + rq;
#pragma unroll
      for (int nf = 0; nf < 4; ++nf) {
        const int col = n0 + wc * 64 + nf * 16 + fr;
        Cf[(long)(row + 0) * 1024 + col] = acc[mf][nf][0] * il[mf][0];
        Cf[(long)(row + 1) * 1024 + col] = acc[mf][nf][1] * il[mf][1];
        Cf[(long)(row + 2) * 1024 + col] = acc[mf][nf][2] * il[mf][2];
        Cf[(long)(row + 3) * 1024 + col] = acc[mf][nf][3] * il[mf][3];
      }
    }
  }
}

// ---------------------------------------------------------------------------
extern "C" void kernel_launch(void* const* d_in, const int* in_sizes, int n_in,
                              void* d_out, int out_size, void* d_ws, size_t ws_size,
                              hipStream_t stream) {
  const float* x  = (const float*)d_in[0];
  const float* Wq = (const float*)d_in[1];
  const float* Wk = (const float*)d_in[2];
  const float* Wv = (const float*)d_in[3];
  float* out = (float*)d_out;

  const int Bb = 4, T = 2048, C = 1024;
  const long BT = (long)Bb * T;  // 8192
  const int N3 = 3 * C;          // 3072

  char* ws = (char*)d_ws;
  unsigned short* xb   = (unsigned short*)ws; ws += BT * C * 2;            // 16 MB
  unsigned short* wbuf = (unsigned short*)ws; ws += (long)N3 * C * 2;      // 6 MB
  unsigned short* qkv  = (unsigned short*)ws; ws += BT * N3 * 2;           // 48 MB (v cols unused)
  unsigned short* vT   = (unsigned short*)ws; ws += BT * C * 2;            // 16 MB
  unsigned short* Pu   = (unsigned short*)ws; ws += (long)Bb * T * T * 2;  // 32 MB
  float* lbuf          = (float*)ws;          ws += BT * 4;                // 32 KB

  // 1. merged casts + zero l
  const long nx4 = BT * C / 4, nw4 = (long)C * C / 4;
  cast_all<<<2048, 256, 0, stream>>>(x, Wq, Wk, Wv, xb, lbuf, nx4, nw4, nx4 + 3 * nw4);

  // 2. fused QKV projection (256x384, 1/CU, 4-phase tri-buffer); v -> vT
  gemm_qkv<<<dim3(256, 1, 1), 512, 0, stream>>>(xb, wbuf, qkv, vT);

  // 3. Pu = exp(q k^T / 32) (causal, no-max softmax) + atomic row sums -> l
  gemm128<1><<<dim3(544, 1, 1), 256, 0, stream>>>(qkv, qkv + C, Pu, lbuf);

  // 4. out = (Pu vT) / l (causal K, XCD-banded bn-sweep + per-XCD LPT)
  gemm128<2><<<dim3(512, 1, 1), 256, 0, stream>>>(Pu, vT, out, lbuf);
}

// Round 12
// 147.158 us; speedup vs baseline: 1.0567x; 1.0149x over previous
//
#include <hip/hip_runtime.h>
#include <stdint.h>

typedef __attribute__((ext_vector_type(8))) __bf16 bf16x8;
typedef __attribute__((ext_vector_type(8))) unsigned short ushort8;
typedef __attribute__((ext_vector_type(4))) float f32x4;

static __device__ __forceinline__ unsigned short f2bf(float f) {
  unsigned u = __float_as_uint(f);
  u += 0x7fffu + ((u >> 16) & 1u);
  return (unsigned short)(u >> 16);
}

union U16cast { ushort8 u; bf16x8 b; };
static __device__ __forceinline__ bf16x8 as_bf16x8(ushort8 x) { U16cast t; t.u = x; return t.b; }
static __device__ __forceinline__ bf16x8 ldfrag(const unsigned short* p) {
  return as_bf16x8(*(const ushort8*)p);
}

#define MFMA16(a, b, c) __builtin_amdgcn_mfma_f32_16x16x32_bf16((a), (b), (c), 0, 0, 0)

#define GLD_LDS16(g, l)                                                        \
  __builtin_amdgcn_global_load_lds(                                            \
      (const __attribute__((address_space(1))) void*)(g),                      \
      (__attribute__((address_space(3))) void*)(l), 16, 0, 0)

// ---------------- merged cast f32 -> bf16 + zero l ---------------------------
__global__ __launch_bounds__(256) void cast_all(
    const float* __restrict__ x, const float* __restrict__ Wq,
    const float* __restrict__ Wk, const float* __restrict__ Wv,
    unsigned short* __restrict__ out, float* __restrict__ lzero,
    long nx4, long nw4, long n4) {
  long g = (long)blockIdx.x * blockDim.x + threadIdx.x;
  if (g < 2048) ((float4*)lzero)[g] = (float4){0.f, 0.f, 0.f, 0.f};  // l[8192]=0
  long i = g;
  long stride = (long)gridDim.x * blockDim.x;
  for (; i < n4; i += stride) {
    const float4* src;
    long j = i;
    if (j < nx4) {
      src = (const float4*)x;
    } else {
      j -= nx4;
      if (j < nw4) src = (const float4*)Wq;
      else if (j < 2 * nw4) { src = (const float4*)Wk; j -= nw4; }
      else { src = (const float4*)Wv; j -= 2 * nw4; }
    }
    float4 v = src[j];
    ushort4 o;
    o.x = f2bf(v.x); o.y = f2bf(v.y); o.z = f2bf(v.z); o.w = f2bf(v.w);
    *(ushort4*)(out + i * 4) = o;
  }
}

// ---- QKV GEMM r12: r9 geometry/pipeline, 2 BALANCED phases per K-tile ------
// 256x384, BK=32, grid 256 = 1/CU, tri-buffer stage-kt+2 (depth 1.5 tiles).
// r9/r10 established: per-phase barrier lockstep (alternating {ds_read|MFMA}
// wave-groups) is the win mechanism. r9's phases were UNBALANCED (ph0: 7
// reads/12 MFMA; ph3: 0 reads) — lockstep throughput = max(read,MFMA) per
// phase, so unbalanced phases waste the short pipe. 2-phase split balances:
//   ph0: read a0[4]+b[6] (10x16B ~240cy/SIMD) | 24 MFMA (~233cy/SIMD)
//        stage SA0,SA1,SB0(kt+2)
//   ph1: read a1[4] | 24 MFMA; stage SB1,SB2(kt+2); vmcnt(5) -> tile kt+1
//        ready for next iter (issue->wait distance ~1 tile ~2400cy)
// and halves barrier count 8->4 per kt. Everything else = r9 verbatim.
__global__ __launch_bounds__(512, 2) void gemm_qkv(
    const unsigned short* __restrict__ A, const unsigned short* __restrict__ B,
    unsigned short* __restrict__ qkv, unsigned short* __restrict__ vT) {
  __shared__ __align__(16) unsigned short As[3][8192];    // [buf][256*32] 48 KB
  __shared__ __align__(16) unsigned short Bs[3][12288];   // [buf][384*32] 72 KB

  int wg = blockIdx.x;
  wg = (wg & 7) * 32 + (wg >> 3);            // XCD swizzle, 256 = 8*32
  const int bm = wg >> 3, bn = wg & 7;
  const int m0 = bm << 8;                    // 0..31 * 256
  const int n0 = bn * 384;                   // 0..7  * 384

  const int tid = threadIdx.x;

  const int srow = tid >> 2;                 // 0..127
  const int sseg = (tid & 3) ^ ((srow >> 1) & 3);
  const unsigned short* sa = A + (long)(m0 + srow) * 1024 + sseg * 8;
  const unsigned short* sb = B + (long)(n0 + srow) * 1024 + sseg * 8;
  unsigned short* dA = &As[0][0] + tid * 8;
  unsigned short* dB = &Bs[0][0] + tid * 8;

  // A: 2 rounds of 128 rows; B: 3 rounds of 128 rows. 5 gloads/thread/tile.
#define SA0(kt, bu) GLD_LDS16(sa + (kt) * 32,          dA + (bu) * 8192)
#define SA1(kt, bu) GLD_LDS16(sa + 131072 + (kt) * 32, dA + (bu) * 8192 + 4096)
#define SB0(kt, bu) GLD_LDS16(sb + (kt) * 32,          dB + (bu) * 12288)
#define SB1(kt, bu) GLD_LDS16(sb + 131072 + (kt) * 32, dB + (bu) * 12288 + 4096)
#define SB2(kt, bu) GLD_LDS16(sb + 262144 + (kt) * 32, dB + (bu) * 12288 + 8192)

  const int lane = tid & 63;
  const int w = tid >> 6;
  const int wrm = w >> 2;    // 0..1 (M half: 128 rows)
  const int wcn = w & 3;     // 0..3 (N quarter: 96 cols)
  const int fr = lane & 15;
  const int kb = lane >> 4;
  const int segr = (kb ^ ((fr >> 1) & 3)) << 3;
  const unsigned short* rA = &As[0][0] + (wrm * 128 + fr) * 32 + segr;
  const unsigned short* rB = &Bs[0][0] + (wcn * 96 + fr) * 32 + segr;

  f32x4 acc[8][6];
#pragma unroll
  for (int mf = 0; mf < 8; ++mf)
#pragma unroll
    for (int nf = 0; nf < 6; ++nf)
      acc[mf][nf] = (f32x4){0.f, 0.f, 0.f, 0.f};

  // prologue: tile0 -> buf0, tile1 -> buf1 (steady slot order);
  // wait tile0 complete, keep tile1's 5 loads in flight.
  SA0(0, 0); SA1(0, 0); SB0(0, 0); SB1(0, 0); SB2(0, 0);
  SA0(1, 1); SA1(1, 1); SB0(1, 1); SB1(1, 1); SB2(1, 1);
  asm volatile("s_waitcnt vmcnt(5)" ::: "memory");
  __builtin_amdgcn_s_barrier();
  __builtin_amdgcn_sched_barrier(0);

  int c0 = 0, c2 = 2;                        // read buf, stage buf (kt+2)
#pragma unroll 1
  for (int kt = 0; kt < 32; ++kt) {
    const unsigned short* pA = rA + c0 * 8192;
    const unsigned short* pB = rB + c0 * 12288;
    const int k2 = kt + 2;
    const bool st = (kt < 30);
    bf16x8 a[4], bv[6];

    // -------- ph0: reads a0[4]+b[6]; stage SA0,SA1,SB0; 24 MFMA mh0 ------
#pragma unroll
    for (int mf = 0; mf < 4; ++mf) a[mf] = ldfrag(pA + mf * 512);
#pragma unroll
    for (int nf = 0; nf < 6; ++nf) bv[nf] = ldfrag(pB + nf * 512);
    if (st) { SA0(k2, c2); SA1(k2, c2); SB0(k2, c2); }
    __builtin_amdgcn_s_barrier();
    asm volatile("s_waitcnt lgkmcnt(0)" ::: "memory");
    __builtin_amdgcn_sched_barrier(0);
    __builtin_amdgcn_s_setprio(1);
#pragma unroll
    for (int mf = 0; mf < 4; ++mf)
#pragma unroll
      for (int nf = 0; nf < 6; ++nf)
        acc[mf][nf] = MFMA16(a[mf], bv[nf], acc[mf][nf]);
    __builtin_amdgcn_s_setprio(0);
    __builtin_amdgcn_s_barrier();

    // -------- ph1: reads a1[4]; stage SB1,SB2; vmcnt boundary; 24 MFMA mh1
#pragma unroll
    for (int mf = 0; mf < 4; ++mf) a[mf] = ldfrag(pA + 2048 + mf * 512);
    if (st) { SB1(k2, c2); SB2(k2, c2); }
    if (kt <= 29)      asm volatile("s_waitcnt vmcnt(5)" ::: "memory");
    else if (kt == 30) asm volatile("s_waitcnt vmcnt(0)" ::: "memory");
    __builtin_amdgcn_s_barrier();
    asm volatile("s_waitcnt lgkmcnt(0)" ::: "memory");
    __builtin_amdgcn_sched_barrier(0);
    __builtin_amdgcn_s_setprio(1);
#pragma unroll
    for (int mf = 0; mf < 4; ++mf)
#pragma unroll
      for (int nf = 0; nf < 6; ++nf)
        acc[4 + mf][nf] = MFMA16(a[mf], bv[nf], acc[4 + mf][nf]);
    __builtin_amdgcn_s_setprio(0);
    __builtin_amdgcn_s_barrier();

    c0 = (c0 == 2) ? 0 : c0 + 1;
    c2 = (c2 == 2) ? 0 : c2 + 1;
  }
#undef SA0
#undef SA1
#undef SB0
#undef SB1
#undef SB2

  // ---- epilogue (r8-proven): route to qkv (cols<2048) or vT (v region) ----
  const int rq = kb << 2;
#pragma unroll
  for (int mf = 0; mf < 8; ++mf) {
    const int row = m0 + wrm * 128 + mf * 16 + rq;
#pragma unroll
    for (int nf = 0; nf < 6; ++nf) {
      const int colb = n0 + wcn * 96 + nf * 16;   // fragment col base (wave-uniform)
      if (colb < 2048) {
        const int col = colb + fr;
#pragma unroll
        for (int r = 0; r < 4; ++r)
          qkv[(long)(row + r) * 3072 + col] = f2bf(acc[mf][nf][r]);
      } else {
        const int b2 = m0 >> 11;
        const int trow = (m0 & 2047) + wrm * 128 + mf * 16 + rq;
        const int colv = colb - 2048 + fr;
        ushort4 o;
        o.x = f2bf(acc[mf][nf][0]); o.y = f2bf(acc[mf][nf][1]);
        o.z = f2bf(acc[mf][nf][2]); o.w = f2bf(acc[mf][nf][3]);
        *(ushort4*)(vT + ((long)b2 * 1024 + colv) * 2048 + trow) = o;
      }
    }
  }
}

// ---------------- 128x128 GEMM engine for S and PV (r0-proven) --------------
//  MODE 1 S:   triangular grid (544, z fastest): A=q, B=k (stride 3072).
//              Epilogue: Pu = exp(s/32) (causal-masked -> exact 0) stored bf16,
//              plus per-row partial sums reduced over the 16 fr-lanes and
//              atomicAdd'ed into l[b*2048+row].
//  MODE 2 PV:  512 blocks; XCD-banded bn-sweep + per-XCD LPT; causal
//              kend=m0+128; A=Pu, B=vT. Epilogue: out = acc * (1/l[row]);
//              1/l loads+rcp hoisted above the K-loop (r6-proven).
template <int MODE>
__global__ __launch_bounds__(256, 4) void gemm128(
    const unsigned short* __restrict__ A, const unsigned short* __restrict__ Bp,
    void* __restrict__ Cout, float* __restrict__ lbuf) {
  __shared__ __align__(16) unsigned short As[2][4096];
  __shared__ __align__(16) unsigned short Bs[2][4096];

  constexpr int LDA = (MODE == 1) ? 3072 : 2048;

  const int wgid = blockIdx.x;
  int m0, n0, b;
  if constexpr (MODE == 1) {
    b = wgid & 3;
    const int t = wgid >> 2;                    // 0..135
    int bm = 0;
    while ((bm + 2) * (bm + 1) / 2 <= t) ++bm;
    const int bn = t - bm * (bm + 1) / 2;
    m0 = bm << 7; n0 = bn << 7;
  } else {
    const int xcd = wgid & 7;
    const int inner = wgid >> 3;                // 0..63
    const int s = inner >> 5;
    const int rem = inner & 31;
    b = rem >> 3;
    const int bn = rem & 7;
    const int bm = s ? (15 - xcd) : xcd;
    m0 = bm << 7; n0 = bn << 7;
  }

  const unsigned short* Ab = A;
  const unsigned short* Bb = Bp;
  if constexpr (MODE == 1) {
    Ab += (long)b * 2048 * 3072;
    Bb += (long)b * 2048 * 3072;
  } else {
    Ab += (long)b * 2048 * 2048;
    Bb += (long)b * 1024 * 2048;
  }

  const int tid = threadIdx.x;

  const int srow = tid >> 2;                       // 0..63
  const int sseg = (tid & 3) ^ ((srow >> 1) & 3);
  const unsigned short* sa = Ab + (long)(m0 + srow) * LDA + sseg * 8;
  const unsigned short* sb = Bb + (long)(n0 + srow) * LDA + sseg * 8;
  const long sRj = (long)64 * LDA;
  unsigned short* dA = &As[0][0] + tid * 8;
  unsigned short* dB = &Bs[0][0] + tid * 8;

#define STG(kt, s)                                                             \
  do {                                                                         \
    GLD_LDS16(sa + (kt) * 32, dA + (s) * 4096);                                \
    GLD_LDS16(sa + sRj + (kt) * 32, dA + (s) * 4096 + 2048);                   \
    GLD_LDS16(sb + (kt) * 32, dB + (s) * 4096);                                \
    GLD_LDS16(sb + sRj + (kt) * 32, dB + (s) * 4096 + 2048);                   \
  } while (0)

  const int lane = tid & 63;
  const int w = tid >> 6;
  const int wr = w >> 1;
  const int wc = w & 1;
  const int fr = lane & 15;
  const int kb = lane >> 4;
  const unsigned short* rA0 = &As[0][0] + wr * 64 * 32;
  const unsigned short* rB0 = &Bs[0][0] + wc * 64 * 32;

  const int rq = kb << 2;

  // PV-only: hoist loop-invariant 1/l above the K-loop
  float il[4][4];
  if constexpr (MODE == 2) {
    const float* lrow = lbuf + b * 2048;
#pragma unroll
    for (int mf = 0; mf < 4; ++mf) {
      const int row = m0 + wr * 64 + mf * 16 + rq;
#pragma unroll
      for (int r = 0; r < 4; ++r) il[mf][r] = 1.0f / lrow[row + r];
    }
  }

  f32x4 acc[4][4];
#pragma unroll
  for (int mf = 0; mf < 4; ++mf)
#pragma unroll
    for (int nf = 0; nf < 4; ++nf)
      acc[mf][nf] = (f32x4){0.f, 0.f, 0.f, 0.f};

  const int kend = (MODE == 2) ? (m0 + 128) : 1024;
  const int NT = kend >> 5;

  STG(0, 0);
  __syncthreads();

  for (int kt = 0; kt < NT; ++kt) {
    const int s = kt & 1;
    if (kt + 1 < NT) STG(kt + 1, s ^ 1);

    bf16x8 av[4], bvv[4];
#pragma unroll
    for (int mf = 0; mf < 4; ++mf) {
      const int row = mf * 16 + fr;
      const int segr = (kb ^ ((row >> 1) & 3)) << 3;
      av[mf] = ldfrag(rA0 + s * 4096 + row * 32 + segr);
    }
#pragma unroll
    for (int nf = 0; nf < 4; ++nf) {
      const int row = nf * 16 + fr;
      const int segr = (kb ^ ((row >> 1) & 3)) << 3;
      bvv[nf] = ldfrag(rB0 + s * 4096 + row * 32 + segr);
    }

#pragma unroll
    for (int mf = 0; mf < 4; ++mf)
#pragma unroll
      for (int nf = 0; nf < 4; ++nf)
        acc[mf][nf] = MFMA16(av[mf], bvv[nf], acc[mf][nf]);

    __syncthreads();
  }
#undef STG

  if constexpr (MODE == 1) {
    unsigned short* Pu = (unsigned short*)Cout + (long)b * 2048 * 2048;
    float* lrow = lbuf + b * 2048;
#pragma unroll
    for (int mf = 0; mf < 4; ++mf) {
      const int row = m0 + wr * 64 + mf * 16 + rq;
      float psum0 = 0.f, psum1 = 0.f, psum2 = 0.f, psum3 = 0.f;
#pragma unroll
      for (int nf = 0; nf < 4; ++nf) {
        const int col = n0 + wc * 64 + nf * 16 + fr;
        float e0 = (col > row + 0) ? 0.f : __expf(acc[mf][nf][0] * 0.03125f);
        float e1 = (col > row + 1) ? 0.f : __expf(acc[mf][nf][1] * 0.03125f);
        float e2 = (col > row + 2) ? 0.f : __expf(acc[mf][nf][2] * 0.03125f);
        float e3 = (col > row + 3) ? 0.f : __expf(acc[mf][nf][3] * 0.03125f);
        psum0 += e0; psum1 += e1; psum2 += e2; psum3 += e3;
        Pu[(long)(row + 0) * 2048 + col] = f2bf(e0);
        Pu[(long)(row + 1) * 2048 + col] = f2bf(e1);
        Pu[(long)(row + 2) * 2048 + col] = f2bf(e2);
        Pu[(long)(row + 3) * 2048 + col] = f2bf(e3);
      }
      // reduce over the 16 fr-lanes (xor 1,2,4,8 stays in the 16-group)
#pragma unroll
      for (int off = 1; off < 16; off <<= 1) {
        psum0 += __shfl_xor(psum0, off);
        psum1 += __shfl_xor(psum1, off);
        psum2 += __shfl_xor(psum2, off);
        psum3 += __shfl_xor(psum3, off);
      }
      if (fr == 0) {
        atomicAdd(&lrow[row + 0], psum0);
        atomicAdd(&lrow[row + 1], psum1);
        atomicAdd(&lrow[row + 2], psum2);
        atomicAdd(&lrow[row + 3], psum3);
      }
    }
  } else {
    float* Cf = (float*)Cout + (long)b * 2048 * 1024;
#pragma unroll
    for (int mf = 0; mf < 4; ++mf) {
      const int row = m0 + wr * 64 + mf * 16 + rq;
#pragma unroll
      for (int nf = 0; nf < 4; ++nf) {
        const int col = n0 + wc * 64 + nf * 16 + fr;
        Cf[(long)(row + 0) * 1024 + col] = acc[mf][nf][0] * il[mf][0];
        Cf[(long)(row + 1) * 1024 + col] = acc[mf][nf][1] * il[mf][1];
        Cf[(long)(row + 2) * 1024 + col] = acc[mf][nf][2] * il[mf][2];
        Cf[(long)(row + 3) * 1024 + col] = acc[mf][nf][3] * il[mf][3];
      }
    }
  }
}

// ---------------------------------------------------------------------------
extern "C" void kernel_launch(void* const* d_in, const int* in_sizes, int n_in,
                              void* d_out, int out_size, void* d_ws, size_t ws_size,
                              hipStream_t stream) {
  const float* x  = (const float*)d_in[0];
  const float* Wq = (const float*)d_in[1];
  const float* Wk = (const float*)d_in[2];
  const float* Wv = (const float*)d_in[3];
  float* out = (float*)d_out;

  const int Bb = 4, T = 2048, C = 1024;
  const long BT = (long)Bb * T;  // 8192
  const int N3 = 3 * C;          // 3072

  char* ws = (char*)d_ws;
  unsigned short* xb   = (unsigned short*)ws; ws += BT * C * 2;            // 16 MB
  unsigned short* wbuf = (unsigned short*)ws; ws += (long)N3 * C * 2;      // 6 MB
  unsigned short* qkv  = (unsigned short*)ws; ws += BT * N3 * 2;           // 48 MB (v cols unused)
  unsigned short* vT   = (unsigned short*)ws; ws += BT * C * 2;            // 16 MB
  unsigned short* Pu   = (unsigned short*)ws; ws += (long)Bb * T * T * 2;  // 32 MB
  float* lbuf          = (float*)ws;          ws += BT * 4;                // 32 KB

  // 1. merged casts + zero l
  const long nx4 = BT * C / 4, nw4 = (long)C * C / 4;
  cast_all<<<2048, 256, 0, stream>>>(x, Wq, Wk, Wv, xb, lbuf, nx4, nw4, nx4 + 3 * nw4);

  // 2. fused QKV projection (256x384, 1/CU, 2-phase balanced tri-buffer)
  gemm_qkv<<<dim3(256, 1, 1), 512, 0, stream>>>(xb, wbuf, qkv, vT);

  // 3. Pu = exp(q k^T / 32) (causal, no-max softmax) + atomic row sums -> l
  gemm128<1><<<dim3(544, 1, 1), 256, 0, stream>>>(qkv, qkv + C, Pu, lbuf);

  // 4. out = (Pu vT) / l (causal K, XCD-banded bn-sweep + per-XCD LPT)
  gemm128<2><<<dim3(512, 1, 1), 256, 0, stream>>>(Pu, vT, out, lbuf);
}